// Round 8
// baseline (70.349 us; speedup 1.0000x reference)
//
#include <hip/hip_runtime.h>

// B=1, C=32, D=64, H=128, W=128. float32 in/out.
// Reverse scan along D: h = z[d]*_h[d] + (1-z[d])*h_prev, out[d] = h.
//
// R7: Infinity-Cache residency management. Inputs (258 MB) barely exceed the
// 256 MB IC -> self-thrash keeps replay FETCH at 132 MB. Mark z for channels
// 20..31 (48 MB) as NON-TEMPORAL loads so the ALLOCATING footprint drops to
// _h(128) + z[c<20](80) + h0(2) = 210 MB < 256 -> those stay IC-resident
// across graph replays; DRAM = 48 MB nt-z + writes. R4 structure otherwise
// (CHUNK=8 batch loads, nt stores, scalar lanes, 2048 blocks).

#define GRU_C  32
#define GRU_D  64
#define GRU_HW (128 * 128)
#define CHUNK  8
#define NT_C0  20   // channels >= NT_C0 use nontemporal z loads

template <bool NTZ>
__device__ __forceinline__ void gru_body(
    const float* __restrict__ z,
    const float* __restrict__ h,
    const float* __restrict__ h0,
    float* __restrict__ out,
    int c, int p)
{
    const int base = c * (GRU_D * GRU_HW) + p;

    float hp = h0[c * GRU_HW + p];

    for (int d0 = GRU_D - CHUNK; d0 >= 0; d0 -= CHUNK) {
        float zb[CHUNK], hb[CHUNK], ob[CHUNK];

        #pragma unroll
        for (int k = 0; k < CHUNK; ++k) {
            const int idx = base + (d0 + k) * GRU_HW;
            zb[k] = NTZ ? __builtin_nontemporal_load(&z[idx]) : z[idx];
            hb[k] = h[idx];
        }

        #pragma unroll
        for (int k = CHUNK - 1; k >= 0; --k) {
            hp = fmaf(zb[k], hb[k], (1.0f - zb[k]) * hp);
            ob[k] = hp;
        }

        #pragma unroll
        for (int k = 0; k < CHUNK; ++k) {
            __builtin_nontemporal_store(ob[k], &out[base + (d0 + k) * GRU_HW]);
        }
    }
}

__global__ __launch_bounds__(256) void gru_rev_scan_kernel(
    const float* __restrict__ z,
    const float* __restrict__ h,
    const float* __restrict__ h0,
    float* __restrict__ out)
{
    // 64 blocks of 256 threads per channel plane (HW = 16384)
    const int c = blockIdx.x >> 6;
    const int p = ((blockIdx.x & 63) << 8) | threadIdx.x;

    if (c < NT_C0) {
        gru_body<false>(z, h, h0, out, c, p);
    } else {
        gru_body<true>(z, h, h0, out, c, p);
    }
}

extern "C" void kernel_launch(void* const* d_in, const int* in_sizes, int n_in,
                              void* d_out, int out_size, void* d_ws, size_t ws_size,
                              hipStream_t stream) {
    const float* z  = (const float*)d_in[0];
    const float* h  = (const float*)d_in[1];
    const float* h0 = (const float*)d_in[2];
    float* out = (float*)d_out;

    const int total_threads = GRU_C * GRU_HW;  // 524288
    const int block = 256;
    const int grid = total_threads / block;    // 2048

    gru_rev_scan_kernel<<<grid, block, 0, stream>>>(z, h, h0, out);
}

// Round 10
// 62.561 us; speedup vs baseline: 1.1245x; 1.1245x over previous
//
#include <hip/hip_runtime.h>

// B=1, C=32, D=64, H=128, W=128. float32 in/out.
// Reverse scan along D: for d = D-1 .. 0:
//   h = z[d]*_h[d] + (1-z[d])*h_prev;  out[d] = h;  h_prev = h;
//
// R9 = R4/R8 restored (best: 62.5 us); R8's run died to an unresponsive
// container (no data), resubmitting verbatim.
//
// Roofline accounting: request-side traffic (L2 <-> IC/HBM fabric) is
// z(128)+_h(128)+h0(2)+out(131) = 389 MB irreducible. R4 = 389MB/62.5us
// = 6.22 TB/s = 99% of the 6.29 TB/s D2D-copy ceiling measured at the
// same boundary. nt stores (R4's -21%) keep the write stream from
// allocating on the request path; scalar lanes + CHUNK=8 batch loads
// give full launch occupancy (8192 waves) and sufficient MLP.

#define GRU_C  32
#define GRU_D  64
#define GRU_HW (128 * 128)
#define CHUNK  8

__global__ __launch_bounds__(256) void gru_rev_scan_kernel(
    const float* __restrict__ z,
    const float* __restrict__ h,
    const float* __restrict__ h0,
    float* __restrict__ out)
{
    const int tid = blockIdx.x * blockDim.x + threadIdx.x;  // 0 .. C*HW - 1
    const int c = tid >> 14;              // / 16384
    const int p = tid & (GRU_HW - 1);

    const int base = c * (GRU_D * GRU_HW) + p;

    float hp = h0[c * GRU_HW + p];

    for (int d0 = GRU_D - CHUNK; d0 >= 0; d0 -= CHUNK) {
        float zb[CHUNK], hb[CHUNK], ob[CHUNK];

        #pragma unroll
        for (int k = 0; k < CHUNK; ++k) {
            const int idx = base + (d0 + k) * GRU_HW;
            zb[k] = z[idx];
            hb[k] = h[idx];
        }

        #pragma unroll
        for (int k = CHUNK - 1; k >= 0; --k) {
            hp = fmaf(zb[k], hb[k], (1.0f - zb[k]) * hp);
            ob[k] = hp;
        }

        #pragma unroll
        for (int k = 0; k < CHUNK; ++k) {
            __builtin_nontemporal_store(ob[k], &out[base + (d0 + k) * GRU_HW]);
        }
    }
}

extern "C" void kernel_launch(void* const* d_in, const int* in_sizes, int n_in,
                              void* d_out, int out_size, void* d_ws, size_t ws_size,
                              hipStream_t stream) {
    const float* z  = (const float*)d_in[0];
    const float* h  = (const float*)d_in[1];
    const float* h0 = (const float*)d_in[2];
    float* out = (float*)d_out;

    const int total_threads = GRU_C * GRU_HW;  // 524288
    const int block = 256;
    const int grid = total_threads / block;    // 2048

    gru_rev_scan_kernel<<<grid, block, 0, stream>>>(z, h, h0, out);
}